// Round 10
// baseline (177.431 us; speedup 1.0000x reference)
//
#include <hip/hip_runtime.h>

// embeddings [B=2][F=32][N=2359296] f32, labels [B][N] i32, prototypes [12][32] f32
// sums[c][f] = sum_n onehot[c][n] * emb[f][n]  ==  mfma(A=onehot, B=emb)
// mfma_f32_16x16x32_bf16 layout: lane l holds outdim=l&15, k=8*(l>>4)+j (j=0..7);
// C/D: col=l&15, row=(l>>4)*4+reg.
// Ledger: R4/R8=124.2 (reg loads, 33 streams/wave x 128B visits)
//         R5=205 SPILL | R7=158 nt broke L2 merge | R9=157 remap (VGPR pressure)
// This round: LDS-staged COALESCED loads — each global_load_lds instruction
// reads 1KB contiguous from ONE feature stream (vs 16 streams x 64B). Only
// untried DRAM-visible pattern change. Zero VGPR data cost for staging.
#define B_        2
#define F_        32
#define C_        12
#define NVOX      2359296L
#define THREADS   256
#define TILE_VOX  256                  // voxels per LDS tile
#define TILES_PB  9                    // tiles per block -> 2304 voxels/block
#define BLOCK_SPAN (TILE_VOX * TILES_PB)
#define NBLK      1024                 // 2048 total blocks (x2 batches)
#define NREP      16                   // replicated global accumulators
#define PADF      260                  // floats per LDS row (1040B): 2-way banks max

#define AS1 __attribute__((address_space(1)))
#define AS3 __attribute__((address_space(3)))

typedef __attribute__((ext_vector_type(8))) short short8;   // 8 bf16 (4 VGPRs)
typedef __attribute__((ext_vector_type(4))) float f32x4;

union ABu { short8 s; __bf16 h[8]; unsigned u[4]; };

__global__ __launch_bounds__(THREADS)
void accum_staged(const float* __restrict__ emb,
                  const int*   __restrict__ labels,
                  float*       __restrict__ g_sums,   // [NREP][B][C*F]
                  float*       __restrict__ g_cnts) { // [NREP][B][C]
    const int b    = blockIdx.y;
    const int tid  = threadIdx.x;
    const int wv   = tid >> 6;
    const int lane = tid & 63;
    const int fcol = lane & 15;        // feature col (and one-hot class row)
    const int kgrp = lane >> 4;        // 0..3, k-base = kgrp*8
    const int rep  = blockIdx.x & (NREP - 1);

    const long base = (long)blockIdx.x * BLOCK_SPAN;

    __shared__ float tile[32 * PADF];  // 33280 B; row f = feature f's 256 voxels

    // wave wv stages features wv*8 .. wv*8+7; per-lane global src is contiguous
    const float* sbase = emb + ((long)(b * F_ + wv * 8)) * NVOX + base + lane * 4;
    const int*   lab   = labels + (long)b * NVOX + base + (kgrp << 3);

    ABu ones;
#pragma unroll
    for (int p = 0; p < 4; ++p) ones.u[p] = 0x3F803F80u;   // bf16 1.0 pairs

    f32x4 acc0 = {0.f, 0.f, 0.f, 0.f};   // sums, features 0..15
    f32x4 acc1 = {0.f, 0.f, 0.f, 0.f};   // sums, features 16..31
    f32x4 acc2 = {0.f, 0.f, 0.f, 0.f};   // counts

    for (int t = 0; t < TILES_PB; ++t) {
        // ---- stage: 8 x 1KB contiguous single-stream reads per wave ----
        const float* sb = sbase + t * TILE_VOX;
#pragma unroll
        for (int q = 0; q < 8; ++q) {
            __builtin_amdgcn_global_load_lds(
                (const AS1 void*)(sb + (long)q * NVOX),
                (AS3 void*)&tile[(wv * 8 + q) * PADF],
                16, 0, 0);
        }
        __syncthreads();   // drains vmcnt -> tile fully staged (m97 pattern)

        // ---- compute: 8 K-steps from LDS (+ broadcast labels from global) ----
        const int* lt = lab + t * TILE_VOX;
#pragma unroll 2
        for (int s = 0; s < 8; ++s) {
            int4 L0 = *(const int4*)(lt + s * 32);
            int4 L1 = *(const int4*)(lt + s * 32 + 4);

            const float* r0 = &tile[fcol * PADF + s * 32 + (kgrp << 3)];
            const float* r1 = &tile[(fcol + 16) * PADF + s * 32 + (kgrp << 3)];
            float4 v00 = *(const float4*)(r0);
            float4 v01 = *(const float4*)(r0 + 4);
            float4 v10 = *(const float4*)(r1);
            float4 v11 = *(const float4*)(r1 + 4);

            // A fragment: onehot[row=fcol][k] as bf16 {0,1}
            ABu a;
            {
                const int r = fcol;
                unsigned m0 = (min(L0.x, 11) == r) ? 0x3F80u : 0u;
                unsigned m1 = (min(L0.y, 11) == r) ? 0x3F80u : 0u;
                unsigned m2 = (min(L0.z, 11) == r) ? 0x3F80u : 0u;
                unsigned m3 = (min(L0.w, 11) == r) ? 0x3F80u : 0u;
                unsigned m4 = (min(L1.x, 11) == r) ? 0x3F80u : 0u;
                unsigned m5 = (min(L1.y, 11) == r) ? 0x3F80u : 0u;
                unsigned m6 = (min(L1.z, 11) == r) ? 0x3F80u : 0u;
                unsigned m7 = (min(L1.w, 11) == r) ? 0x3F80u : 0u;
                a.u[0] = m0 | (m1 << 16);
                a.u[1] = m2 | (m3 << 16);
                a.u[2] = m4 | (m5 << 16);
                a.u[3] = m6 | (m7 << 16);
            }

            // B fragments: f32 -> bf16 (RNE)
            ABu b0, b1;
            b0.h[0] = (__bf16)v00.x; b0.h[1] = (__bf16)v00.y;
            b0.h[2] = (__bf16)v00.z; b0.h[3] = (__bf16)v00.w;
            b0.h[4] = (__bf16)v01.x; b0.h[5] = (__bf16)v01.y;
            b0.h[6] = (__bf16)v01.z; b0.h[7] = (__bf16)v01.w;
            b1.h[0] = (__bf16)v10.x; b1.h[1] = (__bf16)v10.y;
            b1.h[2] = (__bf16)v10.z; b1.h[3] = (__bf16)v10.w;
            b1.h[4] = (__bf16)v11.x; b1.h[5] = (__bf16)v11.y;
            b1.h[6] = (__bf16)v11.z; b1.h[7] = (__bf16)v11.w;

            acc0 = __builtin_amdgcn_mfma_f32_16x16x32_bf16(a.s, b0.s,   acc0, 0, 0, 0);
            acc1 = __builtin_amdgcn_mfma_f32_16x16x32_bf16(a.s, b1.s,   acc1, 0, 0, 0);
            acc2 = __builtin_amdgcn_mfma_f32_16x16x32_bf16(a.s, ones.s, acc2, 0, 0, 0);
        }
        __syncthreads();   // before next stage overwrites the tile
    }

    // ---- block reduction: LDS atomics (distinct addresses within a wave) ----
    __shared__ float lsum[16 * 32];
    __shared__ float lcnt[16];
    for (int i = tid; i < 16 * 32; i += THREADS) lsum[i] = 0.f;
    if (tid < 16) lcnt[tid] = 0.f;
    __syncthreads();

#pragma unroll
    for (int r = 0; r < 4; ++r) {
        const int c = (kgrp << 2) + r;          // D row = class
        atomicAdd(&lsum[c * 32 + fcol],      acc0[r]);
        atomicAdd(&lsum[c * 32 + 16 + fcol], acc1[r]);
    }
    if (fcol == 0) {
#pragma unroll
        for (int r = 0; r < 4; ++r) atomicAdd(&lcnt[(kgrp << 2) + r], acc2[r]);
    }
    __syncthreads();

    // flush to replicated global accumulators (rep = blockIdx.x & 15)
    float* gs = g_sums + ((long)rep * B_ + b) * (C_ * F_);
    float* gc = g_cnts + ((long)rep * B_ + b) * C_;
    for (int i = tid; i < C_ * F_; i += THREADS)
        atomicAdd(&gs[i], lsum[i]);
    if (tid < C_)
        atomicAdd(&gc[tid], lcnt[tid]);
}

__global__ void finalize_kernel(const float* __restrict__ g_sums,
                                const float* __restrict__ g_cnts,
                                const float* __restrict__ proto,
                                float*       __restrict__ out) {
    const int idx = threadIdx.x;               // 0..383 = c*F + f
    if (idx >= C_ * F_) return;
    const int c = idx / F_;
    float p = proto[idx];
#pragma unroll
    for (int b = 0; b < B_; ++b) {
        float cnt = 0.f, s = 0.f;
#pragma unroll
        for (int rep = 0; rep < NREP; ++rep) {
            s   += g_sums[((long)rep * B_ + b) * (C_ * F_) + idx];
            cnt += g_cnts[((long)rep * B_ + b) * C_ + c];
        }
        if (cnt > 0.f) p = 0.9f * p + 0.1f * (s / cnt);
    }
    out[idx] = p;
}

extern "C" void kernel_launch(void* const* d_in, const int* in_sizes, int n_in,
                              void* d_out, int out_size, void* d_ws, size_t ws_size,
                              hipStream_t stream) {
    const float* emb    = (const float*)d_in[0];
    const int*   labels = (const int*)d_in[1];
    const float* proto  = (const float*)d_in[2];
    float*       out    = (float*)d_out;

    float* g_sums = (float*)d_ws;                      // NREP*B*C*F floats
    float* g_cnts = g_sums + NREP * B_ * C_ * F_;      // NREP*B*C floats

    (void)hipMemsetAsync(d_ws, 0,
                   (size_t)(NREP * B_ * (C_ * F_ + C_)) * sizeof(float), stream);

    dim3 grid(NBLK, B_);
    accum_staged<<<grid, THREADS, 0, stream>>>(emb, labels, g_sums, g_cnts);
    finalize_kernel<<<1, C_ * F_, 0, stream>>>(g_sums, g_cnts, proto, out);
}